// Round 4
// baseline (9848.752 us; speedup 1.0000x reference)
//
#include <hip/hip_runtime.h>

// MatchLSTM forward (Round 4).
// Phase A: 5 fp32 tiled GEMM dispatches (unchanged, verified).
// Phase B: ONE persistent kernel, 128 blocks x 256 threads, 64 steps.
//   Round-3 lesson: __threadfence() per barrier = buffer_inv of L1+L2 ->
//   all read-only data (50 MB/step) refetched from LLC at high latency ->
//   108 us/step. Round 4: cross-block data (a_buf, h_m only) moves via
//   sc0/sc1 coherent loads/stores; read-only data stays L2-cached; barrier
//   has NO cache-wide fence. wm GEMM fused into attention block (h_m[b,:]
//   is only 2 KB) -> 2 barriers/step instead of 3.

#define DEV static __device__ __forceinline__

DEV float fast_sigmoid(float x) { return 1.0f / (1.0f + __expf(-x)); }
DEV float fast_tanh(float x)    { return 1.0f - 2.0f / (__expf(2.0f * x) + 1.0f); }

// ---- coherent (cross-XCD) access helpers: bypass L1/L2, hit LLC ----------
DEV float2 cload2(const float* p) {
    float2 r;
    asm volatile("global_load_dwordx2 %0, %1, off sc0 sc1\n\ts_waitcnt vmcnt(0)"
                 : "=&v"(r) : "v"(p) : "memory");
    return r;
}
DEV float4 cload4(const float* p) {
    float4 r;
    asm volatile("global_load_dwordx4 %0, %1, off sc0 sc1\n\ts_waitcnt vmcnt(0)"
                 : "=&v"(r) : "v"(p) : "memory");
    return r;
}
DEV void cstore(float* p, float v) {
    asm volatile("global_store_dword %0, %1, off sc0 sc1" :: "v"(p), "v"(v) : "memory");
}
DEV int cload_int(const int* p) {
    int r;
    asm volatile("global_load_dword %0, %1, off sc0 sc1\n\ts_waitcnt vmcnt(0)"
                 : "=&v"(r) : "v"(p) : "memory");
    return r;
}

// Grid barrier WITHOUT cache-wide fences. Correctness: all cross-block data
// is written with sc0/sc1 write-through stores; every wave drains vmcnt
// before arrive, so data is at the coherent point before the counter bumps;
// readers use sc0/sc1 loads. Read-only data is never stale.
DEV void gsync(int* bar, int target)
{
    asm volatile("s_waitcnt vmcnt(0) lgkmcnt(0)" ::: "memory");
    __syncthreads();
    if (threadIdx.x == 0) {
        __hip_atomic_fetch_add(bar, 1, __ATOMIC_RELAXED, __HIP_MEMORY_SCOPE_AGENT);
        while (cload_int(bar) < target)
            __builtin_amdgcn_s_sleep(2);
    }
    __syncthreads();
}

// ---------------------------------------------------------------------------
// Phase A GEMM (unchanged from Round 1; verified passing).
// ---------------------------------------------------------------------------
template<int BM, int NG, int MODE, int GATHER>
__global__ __launch_bounds__(256) void gemm3_kernel(
    const float* __restrict__ A, const int* __restrict__ gidx, int lda,
    const float* __restrict__ W, int ldw, int K,
    const float* __restrict__ bias1, const float* __restrict__ bias2,
    const float* __restrict__ add3, float* __restrict__ out)
{
    constexpr int BK = 32;
    constexpr int TM = BM / 16;
    constexpr int TJ = 2;
    constexpr int AP = BM + 4;
    constexpr int WP = NG * 32 + 4;
    __shared__ __align__(16) float As[BK][AP];
    __shared__ __align__(16) float Wsh[BK][WP];

    const int tid = threadIdx.x;
    const int ty = tid >> 4;
    const int tx = tid & 15;
    const int m0 = blockIdx.x * BM;
    const int j0 = blockIdx.y * 32;

    float acc[TM][TJ][NG];
#pragma unroll
    for (int im = 0; im < TM; ++im)
#pragma unroll
        for (int ij = 0; ij < TJ; ++ij)
#pragma unroll
            for (int g = 0; g < NG; ++g) acc[im][ij][g] = 0.0f;

    for (int k0 = 0; k0 < K; k0 += BK) {
#pragma unroll
        for (int i = tid; i < BM * BK; i += 256) {
            int r = i >> 5, c = i & 31;
            int gk = k0 + c;
            float v = 0.0f;
            if (gk < K) {
                int arow = GATHER ? gidx[m0 + r] : (m0 + r);
                v = A[arow * lda + gk];
            }
            As[c][r] = v;
        }
#pragma unroll
        for (int i = tid; i < NG * 32 * BK; i += 256) {
            int rl = i >> 5, c = i & 31;
            int g = rl >> 5, jj = rl & 31;
            int row = (g == 0 ? 0 : (g == 1 ? 1024 : 1536)) + j0 + jj;
            int gk = k0 + c;
            float v = (gk < K) ? W[row * ldw + gk] : 0.0f;
            Wsh[c][rl] = v;
        }
        __syncthreads();
#pragma unroll
        for (int kk = 0; kk < BK; ++kk) {
            float av[TM];
            if constexpr (TM == 4) {
                float4 t4 = *reinterpret_cast<const float4*>(&As[kk][ty * 4]);
                av[0] = t4.x; av[1] = t4.y; av[2] = t4.z; av[3] = t4.w;
            } else {
                float2 t2 = *reinterpret_cast<const float2*>(&As[kk][ty * 2]);
                av[0] = t2.x; av[1] = t2.y;
            }
#pragma unroll
            for (int g = 0; g < NG; ++g) {
                float2 w2 = *reinterpret_cast<const float2*>(&Wsh[kk][g * 32 + tx * 2]);
#pragma unroll
                for (int im = 0; im < TM; ++im) {
                    acc[im][0][g] += av[im] * w2.x;
                    acc[im][1][g] += av[im] * w2.y;
                }
            }
        }
        __syncthreads();
    }

#pragma unroll
    for (int im = 0; im < TM; ++im) {
        int m = m0 + ty * TM + im;
#pragma unroll
        for (int ij = 0; ij < TJ; ++ij) {
            int j = j0 + tx * TJ + ij;
            if constexpr (MODE == 3) {
                out[m * 512 + j] = acc[im][ij][0];
            } else if constexpr (MODE == 1) {
                out[(m * 3 + 0) * 512 + j] = acc[im][ij][0] + bias1[j] + bias2[j];
                out[(m * 3 + 1) * 512 + j] = acc[im][ij][1] + bias1[1024 + j] + bias2[1024 + j];
                out[(m * 3 + 2) * 512 + j] = acc[im][ij][2] + bias1[1536 + j] + bias2[1536 + j];
            } else if constexpr (MODE == 0) {
                float gi = acc[im][ij][0] + bias1[j] + bias2[j];
                float gg = acc[im][ij][1] + bias1[1024 + j] + bias2[1024 + j];
                float go = acc[im][ij][2] + bias1[1536 + j] + bias2[1536 + j];
                float c  = fast_sigmoid(gi) * fast_tanh(gg);
                out[m * 512 + j] = fast_sigmoid(go) * fast_tanh(c);
            } else {
                float gi = acc[im][ij][0] + add3[(m * 3 + 0) * 512 + j];
                float gg = acc[im][ij][1] + add3[(m * 3 + 1) * 512 + j];
                float go = acc[im][ij][2] + add3[(m * 3 + 2) * 512 + j];
                float c  = fast_sigmoid(gi) * fast_tanh(gg);
                out[m * 512 + j] = fast_sigmoid(go) * fast_tanh(c);
            }
        }
    }
}

// ---------------------------------------------------------------------------
// Phase B v2: 128 blocks x 256 threads, 2 barriers/step.
//  P2 (block = b): wm[b,:] computed in-block (h_m[b,:] via 2KB coherent read,
//      Wm from warm L2); scores -> softmax -> a[b,:]; coherent-store a.
//  P3 (block = (b-half, 8-j slice)): gates GEMM; coherent-stage a, coherent-
//      store h_m. pre_m_h / Wih_m / pre_s / h_s / pre_t stay plain (read-only).
// ---------------------------------------------------------------------------
__global__ __launch_bounds__(256) void phaseB_kernel(
    const float* __restrict__ pre_s, const float* __restrict__ pre_t,
    const float* __restrict__ h_s,   const float* __restrict__ pre_m_h,
    const float* __restrict__ Wm,    const float* __restrict__ Wih_m,
    const float* __restrict__ w_e,
    const float* __restrict__ fc_w,  const float* __restrict__ fc_b,
    float* __restrict__ h_m, float* __restrict__ a_buf,
    int* __restrict__ bar, float* __restrict__ out)
{
    __shared__ __align__(16) float smem[(64 + 24) * 132];   // 46.5 KB
    float* Sh   = smem;               // [64][132] P3 activation tile
    float* Wsh  = smem + 64 * 132;    // [24][132] P3 weight tile
    float* hm   = smem;               // [512] P2: h_m[b,:]
    float* base = smem + 512;         // [512] P2: pre_t + wm
    float* wesh = smem + 1024;        // [512] P2: w_e
    float* sc   = smem + 1536;        // [64]  P2: scores/alpha

    const int w    = blockIdx.x;
    const int tid  = threadIdx.x;
    const int wv   = tid >> 6;
    const int lane = tid & 63;
    const int b0   = (w & 1) * 64;
    const int j0   = (w >> 1) * 8;
    int bcount = 0;

    for (int k = 0; k < 64; ++k) {
        // ================= P2: attention for b = w =================
        {
            const int b = w;
            if (k > 0) {
                float2 hv = cload2(&h_m[b * 512 + tid * 2]);
                hm[tid * 2] = hv.x; hm[tid * 2 + 1] = hv.y;
            }
#pragma unroll
            for (int r = 0; r < 2; ++r) { int h = tid + r * 256; wesh[h] = w_e[h]; }
            __syncthreads();

            // wm[j] for j = 2tid, 2tid+1 (Wm rows from L2, hm broadcast from LDS)
            float wm0 = 0.f, wm1 = 0.f;
            if (k > 0) {
                const float* w0p = &Wm[(2 * tid) * 512];
                const float* w1p = w0p + 512;
#pragma unroll 4
                for (int h4 = 0; h4 < 128; ++h4) {
                    float4 hv = *(const float4*)&hm[h4 * 4];
                    float4 wa = *(const float4*)&w0p[h4 * 4];
                    float4 wb = *(const float4*)&w1p[h4 * 4];
                    wm0 += hv.x * wa.x + hv.y * wa.y + hv.z * wa.z + hv.w * wa.w;
                    wm1 += hv.x * wb.x + hv.y * wb.y + hv.z * wb.z + hv.w * wb.w;
                }
            }
            const float* pt = &pre_t[((size_t)k * 128 + b) * 512];
            base[2 * tid]     = pt[2 * tid]     + wm0;
            base[2 * tid + 1] = pt[2 * tid + 1] + wm1;
            __syncthreads();

            // scores over t
            for (int tt = 0; tt < 16; ++tt) {
                int t = wv * 16 + tt;
                const float* ps = pre_s + ((size_t)t * 128 + b) * 512;
                float p = 0.0f;
#pragma unroll
                for (int u = 0; u < 8; ++u) {
                    int h = lane + 64 * u;
                    p += wesh[h] * fast_tanh(ps[h] + base[h]);
                }
#pragma unroll
                for (int off = 32; off; off >>= 1) p += __shfl_xor(p, off);
                if (lane == 0) sc[t] = p;
            }
            __syncthreads();
            if (wv == 0) {
                float s = sc[lane];
                float mx = s;
#pragma unroll
                for (int off = 32; off; off >>= 1) mx = fmaxf(mx, __shfl_xor(mx, off));
                float e = __expf(s - mx);
                float sum = e;
#pragma unroll
                for (int off = 32; off; off >>= 1) sum += __shfl_xor(sum, off);
                sc[lane] = e / sum;
            }
            __syncthreads();
#pragma unroll
            for (int r = 0; r < 2; ++r) {
                int h = tid + r * 256;
                float acc = 0.0f;
                for (int t = 0; t < 64; ++t)
                    acc += sc[t] * h_s[((size_t)t * 128 + b) * 512 + h];
                cstore(&a_buf[b * 512 + h], acc);
            }
        }
        gsync(bar, (++bcount) * 128);

        // ================= P3: gates GEMM =================
        {
            float acc[2][3] = {};
            for (int kc = 0; kc < 4; ++kc) {
                const int k0c = kc * 128;
                // coherent batched stage of a_buf tile (8 rows/thread-group)
                {
                    const int r0 = tid >> 5, cq = tid & 31;
                    const float* pa = &a_buf[(size_t)(b0 + r0) * 512 + k0c + cq * 4];
                    float4 q0, q1, q2, q3, q4, q5, q6, q7;
                    asm volatile(
                        "global_load_dwordx4 %0, %8, off sc0 sc1\n\t"
                        "global_load_dwordx4 %1, %9, off sc0 sc1\n\t"
                        "global_load_dwordx4 %2, %10, off sc0 sc1\n\t"
                        "global_load_dwordx4 %3, %11, off sc0 sc1\n\t"
                        "global_load_dwordx4 %4, %12, off sc0 sc1\n\t"
                        "global_load_dwordx4 %5, %13, off sc0 sc1\n\t"
                        "global_load_dwordx4 %6, %14, off sc0 sc1\n\t"
                        "global_load_dwordx4 %7, %15, off sc0 sc1\n\t"
                        "s_waitcnt vmcnt(0)"
                        : "=&v"(q0), "=&v"(q1), "=&v"(q2), "=&v"(q3),
                          "=&v"(q4), "=&v"(q5), "=&v"(q6), "=&v"(q7)
                        : "v"(pa),         "v"(pa + 4096),  "v"(pa + 8192),
                          "v"(pa + 12288), "v"(pa + 16384), "v"(pa + 20480),
                          "v"(pa + 24576), "v"(pa + 28672)
                        : "memory");
                    *(float4*)&Sh[(r0 +  0) * 132 + cq * 4] = q0;
                    *(float4*)&Sh[(r0 +  8) * 132 + cq * 4] = q1;
                    *(float4*)&Sh[(r0 + 16) * 132 + cq * 4] = q2;
                    *(float4*)&Sh[(r0 + 24) * 132 + cq * 4] = q3;
                    *(float4*)&Sh[(r0 + 32) * 132 + cq * 4] = q4;
                    *(float4*)&Sh[(r0 + 40) * 132 + cq * 4] = q5;
                    *(float4*)&Sh[(r0 + 48) * 132 + cq * 4] = q6;
                    *(float4*)&Sh[(r0 + 56) * 132 + cq * 4] = q7;
                }
                for (int v = tid; v < 768; v += 256) {
                    int row = v >> 5, cq = v & 31;        // row in [0,24)
                    int g = row >> 3, j = row & 7;
                    int wrow = (g == 0 ? 0 : (g == 1 ? 1024 : 1536)) + j0 + j;
                    *(float4*)&Wsh[row * 132 + cq * 4] =
                        *(const float4*)&Wih_m[(size_t)wrow * 1024 + k0c + cq * 4];
                }
                __syncthreads();
                const float* sr = &Sh[lane * 132];
#pragma unroll
                for (int cq = 0; cq < 32; ++cq) {
                    float4 s = *(const float4*)&sr[cq * 4];
#pragma unroll
                    for (int jj = 0; jj < 2; ++jj)
#pragma unroll
                        for (int g = 0; g < 3; ++g) {
                            float4 ww = *(const float4*)&Wsh[(g * 8 + wv * 2 + jj) * 132 + cq * 4];
                            acc[jj][g] += s.x * ww.x + s.y * ww.y + s.z * ww.z + s.w * ww.w;
                        }
                }
                __syncthreads();
            }
            const size_t m = (size_t)k * 128 + b0 + lane;
#pragma unroll
            for (int jj = 0; jj < 2; ++jj) {
                int j = j0 + wv * 2 + jj;
                float gi = acc[jj][0] + pre_m_h[(m * 3 + 0) * 512 + j];
                float gg = acc[jj][1] + pre_m_h[(m * 3 + 1) * 512 + j];
                float go = acc[jj][2] + pre_m_h[(m * 3 + 2) * 512 + j];
                float c  = fast_sigmoid(gi) * fast_tanh(gg);
                cstore(&h_m[(b0 + lane) * 512 + j], fast_sigmoid(go) * fast_tanh(c));
            }
        }
        gsync(bar, (++bcount) * 128);
    }

    // ================= FC epilogue =================
    if (w < 96) {
        int idx = w * 4 + wv;                 // 0..383
        int b = idx / 3, c = idx % 3;
        float4 h0 = cload4(&h_m[b * 512 + lane * 8]);
        float4 h1 = cload4(&h_m[b * 512 + lane * 8 + 4]);
        float4 w0 = *(const float4*)&fc_w[c * 512 + lane * 8];
        float4 w1 = *(const float4*)&fc_w[c * 512 + lane * 8 + 4];
        float p = h0.x * w0.x + h0.y * w0.y + h0.z * w0.z + h0.w * w0.w
                + h1.x * w1.x + h1.y * w1.y + h1.z * w1.z + h1.w * w1.w;
#pragma unroll
        for (int off = 32; off; off >>= 1) p += __shfl_xor(p, off);
        if (lane == 0) out[b * 3 + c] = p + fc_b[c];
    }
}

__global__ void zero_kernel(float* __restrict__ p, int n)
{
    int i = blockIdx.x * 256 + threadIdx.x;
    if (i < n) p[i] = 0.0f;
}

extern "C" void kernel_launch(void* const* d_in, const int* in_sizes, int n_in,
                              void* d_out, int out_size, void* d_ws, size_t ws_size,
                              hipStream_t stream)
{
    (void)in_sizes; (void)n_in; (void)out_size;
    const int*   premise    = (const int*)d_in[0];
    const int*   hypothesis = (const int*)d_in[2];
    const float* embed  = (const float*)d_in[4];
    const float* w_e    = (const float*)d_in[5];
    const float* Ws     = (const float*)d_in[6];
    const float* Wt     = (const float*)d_in[7];
    const float* Wm     = (const float*)d_in[8];
    const float* Wih_p  = (const float*)d_in[9];
    const float* bih_p  = (const float*)d_in[10];
    const float* bhh_p  = (const float*)d_in[11];
    const float* Wih_h  = (const float*)d_in[12];
    const float* bih_h  = (const float*)d_in[13];
    const float* bhh_h  = (const float*)d_in[14];
    const float* Wih_m  = (const float*)d_in[15];
    const float* bih_m  = (const float*)d_in[16];
    const float* bhh_m  = (const float*)d_in[17];
    const float* fc_w   = (const float*)d_in[18];
    const float* fc_b   = (const float*)d_in[19];

    float* ws      = (float*)d_ws;
    float* h_s     = ws;                      // 8192*512
    float* h_t     = h_s    + 4194304;
    float* pre_s   = h_t    + 4194304;
    float* pre_t   = pre_s  + 4194304;
    float* pre_m_h = pre_t  + 4194304;        // 8192*3*512
    float* h_m     = pre_m_h + 12582912;      // 128*512
    float* a_buf   = h_m    + 65536;          // 128*512
    int*   bar     = (int*)(a_buf + 65536);   // barrier counter
    float* outp    = (float*)d_out;
    if (ws_size < (size_t)(29491200 + 64) * 4) return;

    dim3 blk(256);

    // zero the barrier counter (d_ws is 0xAA-poisoned before every launch)
    zero_kernel<<<1, blk, 0, stream>>>((float*)bar, 64);

    // Phase A (parallel)
    gemm3_kernel<64, 3, 0, 1><<<dim3(128, 16), blk, 0, stream>>>(
        embed, premise, 300, Wih_p, 300, 300, bih_p, bhh_p, nullptr, h_s);
    gemm3_kernel<64, 3, 0, 1><<<dim3(128, 16), blk, 0, stream>>>(
        embed, hypothesis, 300, Wih_h, 300, 300, bih_h, bhh_h, nullptr, h_t);
    gemm3_kernel<64, 1, 3, 0><<<dim3(128, 16), blk, 0, stream>>>(
        h_s, nullptr, 512, Ws, 512, 512, nullptr, nullptr, nullptr, pre_s);
    gemm3_kernel<64, 1, 3, 0><<<dim3(128, 16), blk, 0, stream>>>(
        h_t, nullptr, 512, Wt, 512, 512, nullptr, nullptr, nullptr, pre_t);
    gemm3_kernel<64, 3, 1, 0><<<dim3(128, 16), blk, 0, stream>>>(
        h_t, nullptr, 512, Wih_m + 512, 1024, 512, bih_m, bhh_m, nullptr, pre_m_h);

    // Phase B (sequential, one persistent dispatch, lightweight grid barrier)
    phaseB_kernel<<<dim3(128), blk, 0, stream>>>(
        pre_s, pre_t, h_s, pre_m_h, Wm, Wih_m, w_e, fc_w, fc_b,
        h_m, a_buf, bar, outp);
}

// Round 6
// 4865.184 us; speedup vs baseline: 2.0243x; 2.0243x over previous
//
#include <hip/hip_runtime.h>

// MatchLSTM forward (Round 6) = Round 5 + trans_pack loop-bound fix.
// Round-5 failure: pack loop wrote only q<32 of 64 packed rows per tile ->
// half of WmT2/W3t2 left uninitialized -> NaN on correctness call.
//
// Structure: phase B is INDEPENDENT per batch element (one block per b,
// state in LDS, no grid sync — rounds 3/4 showed grid-sync costs 100+us/step).
// Per-step GEMV weights pre-transposed + bf16-packed (j-contiguous).

#define DEV static __device__ __forceinline__

DEV float fast_sigmoid(float x) { return 1.0f / (1.0f + __expf(-x)); }
DEV float fast_tanh(float x)    { return 1.0f - 2.0f / (__expf(2.0f * x) + 1.0f); }

// bf16 pack/unpack (RTNE pack; unpack = shift into fp32 exponent position)
DEV unsigned f2bf(float x) {
    unsigned v = __float_as_uint(x);
    return (v + 0x7FFFu + ((v >> 16) & 1u)) >> 16;
}
DEV float blo(unsigned u) { return __uint_as_float(u << 16); }
DEV float bhi(unsigned u) { return __uint_as_float(u & 0xFFFF0000u); }

// ---------------------------------------------------------------------------
// Phase A GEMM (unchanged from Round 1; verified passing).
// ---------------------------------------------------------------------------
template<int BM, int NG, int MODE, int GATHER>
__global__ __launch_bounds__(256) void gemm3_kernel(
    const float* __restrict__ A, const int* __restrict__ gidx, int lda,
    const float* __restrict__ W, int ldw, int K,
    const float* __restrict__ bias1, const float* __restrict__ bias2,
    const float* __restrict__ add3, float* __restrict__ out)
{
    constexpr int BK = 32;
    constexpr int TM = BM / 16;
    constexpr int TJ = 2;
    constexpr int AP = BM + 4;
    constexpr int WP = NG * 32 + 4;
    __shared__ __align__(16) float As[BK][AP];
    __shared__ __align__(16) float Wsh[BK][WP];

    const int tid = threadIdx.x;
    const int ty = tid >> 4;
    const int tx = tid & 15;
    const int m0 = blockIdx.x * BM;
    const int j0 = blockIdx.y * 32;

    float acc[TM][TJ][NG];
#pragma unroll
    for (int im = 0; im < TM; ++im)
#pragma unroll
        for (int ij = 0; ij < TJ; ++ij)
#pragma unroll
            for (int g = 0; g < NG; ++g) acc[im][ij][g] = 0.0f;

    for (int k0 = 0; k0 < K; k0 += BK) {
#pragma unroll
        for (int i = tid; i < BM * BK; i += 256) {
            int r = i >> 5, c = i & 31;
            int gk = k0 + c;
            float v = 0.0f;
            if (gk < K) {
                int arow = GATHER ? gidx[m0 + r] : (m0 + r);
                v = A[arow * lda + gk];
            }
            As[c][r] = v;
        }
#pragma unroll
        for (int i = tid; i < NG * 32 * BK; i += 256) {
            int rl = i >> 5, c = i & 31;
            int g = rl >> 5, jj = rl & 31;
            int row = (g == 0 ? 0 : (g == 1 ? 1024 : 1536)) + j0 + jj;
            int gk = k0 + c;
            float v = (gk < K) ? W[row * ldw + gk] : 0.0f;
            Wsh[c][rl] = v;
        }
        __syncthreads();
#pragma unroll
        for (int kk = 0; kk < BK; ++kk) {
            float av[TM];
            if constexpr (TM == 4) {
                float4 t4 = *reinterpret_cast<const float4*>(&As[kk][ty * 4]);
                av[0] = t4.x; av[1] = t4.y; av[2] = t4.z; av[3] = t4.w;
            } else {
                float2 t2 = *reinterpret_cast<const float2*>(&As[kk][ty * 2]);
                av[0] = t2.x; av[1] = t2.y;
            }
#pragma unroll
            for (int g = 0; g < NG; ++g) {
                float2 w2 = *reinterpret_cast<const float2*>(&Wsh[kk][g * 32 + tx * 2]);
#pragma unroll
                for (int im = 0; im < TM; ++im) {
                    acc[im][0][g] += av[im] * w2.x;
                    acc[im][1][g] += av[im] * w2.y;
                }
            }
        }
        __syncthreads();
    }

#pragma unroll
    for (int im = 0; im < TM; ++im) {
        int m = m0 + ty * TM + im;
#pragma unroll
        for (int ij = 0; ij < TJ; ++ij) {
            int j = j0 + tx * TJ + ij;
            if constexpr (MODE == 3) {
                out[m * 512 + j] = acc[im][ij][0];
            } else if constexpr (MODE == 1) {
                out[(m * 3 + 0) * 512 + j] = acc[im][ij][0] + bias1[j] + bias2[j];
                out[(m * 3 + 1) * 512 + j] = acc[im][ij][1] + bias1[1024 + j] + bias2[1024 + j];
                out[(m * 3 + 2) * 512 + j] = acc[im][ij][2] + bias1[1536 + j] + bias2[1536 + j];
            } else if constexpr (MODE == 0) {
                float gi = acc[im][ij][0] + bias1[j] + bias2[j];
                float gg = acc[im][ij][1] + bias1[1024 + j] + bias2[1024 + j];
                float go = acc[im][ij][2] + bias1[1536 + j] + bias2[1536 + j];
                float c  = fast_sigmoid(gi) * fast_tanh(gg);
                out[m * 512 + j] = fast_sigmoid(go) * fast_tanh(c);
            } else {
                float gi = acc[im][ij][0] + add3[(m * 3 + 0) * 512 + j];
                float gg = acc[im][ij][1] + add3[(m * 3 + 1) * 512 + j];
                float go = acc[im][ij][2] + add3[(m * 3 + 2) * 512 + j];
                float c  = fast_sigmoid(gi) * fast_tanh(gg);
                out[m * 512 + j] = fast_sigmoid(go) * fast_tanh(c);
            }
        }
    }
}

// ---------------------------------------------------------------------------
// Transpose + bf16-pack: out[(h/2)][out_col + j] = pack(W[row+j][h], W[row+j][h+1])
// gates=0: single matrix (Wm).  gates=1: blockIdx.z selects gate row-base
// {0,1024,1536} of Wih_m (a-half = cols 0..511) and out column block z*512.
// Each block: 64 j x 128 h tile -> 64 j x 64 packed-pair rows (4096 outputs).
// ---------------------------------------------------------------------------
__global__ __launch_bounds__(256) void trans_pack_kernel(
    const float* __restrict__ W, int ld, int gates,
    unsigned* __restrict__ out, int out_ld)
{
    __shared__ float tile[64][129];
    const int j0 = blockIdx.x * 64;
    const int h0 = blockIdx.y * 128;
    const int g  = blockIdx.z;
    const int row_base = gates ? (g == 0 ? 0 : (g == 1 ? 1024 : 1536)) : 0;
    const int out_col  = gates ? g * 512 : 0;

    for (int i = threadIdx.x; i < 64 * 128; i += 256) {
        int jj = i >> 7, hh = i & 127;
        tile[jj][hh] = W[(size_t)(row_base + j0 + jj) * ld + h0 + hh];
    }
    __syncthreads();
    for (int i = threadIdx.x; i < 4096; i += 256) {       // FIX: was 2048
        int jj = i & 63, q = i >> 6;                      // q in [0,64)
        unsigned lo = f2bf(tile[jj][2 * q]);
        unsigned hi = f2bf(tile[jj][2 * q + 1]);
        out[(size_t)(h0 / 2 + q) * out_ld + out_col + j0 + jj] = lo | (hi << 16);
    }
}

// ---------------------------------------------------------------------------
// Phase B: one block per batch element b, 512 threads, 64 steps, NO grid sync.
// LDS state: hm (h_m row b), av (attention context), base (pre_t + wm), sc.
// Per step: wm GEMV (bf16 WmT2, j-coalesced) -> scores+softmax -> a GEMV ->
// gates GEMV (bf16 W3t2) + pre_m_h -> new hm. FC epilogue in-block.
// ---------------------------------------------------------------------------
__global__ __launch_bounds__(512) void phaseB_kernel(
    const float* __restrict__ pre_s, const float* __restrict__ pre_t,
    const float* __restrict__ h_s,   const float* __restrict__ pre_m_h,
    const unsigned* __restrict__ WmT2, const unsigned* __restrict__ W3t2,
    const float* __restrict__ w_e,
    const float* __restrict__ fc_w,  const float* __restrict__ fc_b,
    float* __restrict__ out)
{
    __shared__ __align__(16) float hm[512];
    __shared__ __align__(16) float av[512];
    __shared__ __align__(16) float base[512];
    __shared__ __align__(16) float wesh[512];
    __shared__ __align__(16) float sc[64];

    const int b    = blockIdx.x;
    const int tid  = threadIdx.x;          // 0..511
    const int wv   = tid >> 6;             // 0..7
    const int lane = tid & 63;

    wesh[tid] = w_e[tid];
    hm[tid]   = 0.0f;
    __syncthreads();

    for (int k = 0; k < 64; ++k) {
        // ---- wm[j=tid] = sum_h hm[h] * Wm[j][h]  (bf16 packed pairs) ----
        float wmj = 0.0f;
        if (k > 0) {
            const unsigned* wp = WmT2 + tid;
#pragma unroll 4
            for (int c = 0; c < 256; c += 4) {
                float4 hA = *(const float4*)&hm[2 * c];
                float4 hB = *(const float4*)&hm[2 * c + 4];
                unsigned u0 = wp[(c + 0) * 512];
                unsigned u1 = wp[(c + 1) * 512];
                unsigned u2 = wp[(c + 2) * 512];
                unsigned u3 = wp[(c + 3) * 512];
                wmj += blo(u0) * hA.x + bhi(u0) * hA.y
                     + blo(u1) * hA.z + bhi(u1) * hA.w
                     + blo(u2) * hB.x + bhi(u2) * hB.y
                     + blo(u3) * hB.z + bhi(u3) * hB.w;
            }
        }
        base[tid] = pre_t[((size_t)k * 128 + b) * 512 + tid] + wmj;
        __syncthreads();

        // ---- scores[t] = sum_h w_e[h] * tanh(pre_s[t,b,h] + base[h]) ----
        for (int tt = 0; tt < 8; ++tt) {
            int t = wv * 8 + tt;
            const float* ps = pre_s + ((size_t)t * 128 + b) * 512;
            float p = 0.0f;
#pragma unroll
            for (int u = 0; u < 8; ++u) {
                int h = lane + 64 * u;
                p += wesh[h] * fast_tanh(ps[h] + base[h]);
            }
#pragma unroll
            for (int off = 32; off; off >>= 1) p += __shfl_xor(p, off);
            if (lane == 0) sc[t] = p;
        }
        __syncthreads();
        if (wv == 0) {                      // softmax over 64 t
            float s = sc[lane], mx = s;
#pragma unroll
            for (int off = 32; off; off >>= 1) mx = fmaxf(mx, __shfl_xor(mx, off));
            float e = __expf(s - mx), sum = e;
#pragma unroll
            for (int off = 32; off; off >>= 1) sum += __shfl_xor(sum, off);
            sc[lane] = e / sum;
        }
        __syncthreads();

        // ---- a[h=tid] = sum_t alpha[t] * h_s[t,b,h] ----
        {
            float aacc = 0.0f;
            const float* hp = h_s + (size_t)b * 512 + tid;
#pragma unroll
            for (int t4 = 0; t4 < 16; ++t4) {
                float4 s4 = *(const float4*)&sc[t4 * 4];
                aacc += s4.x * hp[(size_t)(t4 * 4 + 0) * 65536]
                      + s4.y * hp[(size_t)(t4 * 4 + 1) * 65536]
                      + s4.z * hp[(size_t)(t4 * 4 + 2) * 65536]
                      + s4.w * hp[(size_t)(t4 * 4 + 3) * 65536];
            }
            av[tid] = aacc;
        }
        __syncthreads();

        // ---- gates: gi/gg/go[j=tid] = sum_k a[k] * Wih_m[grow+j][k] ----
        float gi = 0.0f, gg = 0.0f, go = 0.0f;
        {
            const unsigned* wp = W3t2 + tid;
#pragma unroll 2
            for (int c = 0; c < 256; c += 2) {
                float4 aA = *(const float4*)&av[2 * c];
                unsigned ui0 = wp[(c + 0) * 1536];
                unsigned ug0 = wp[(c + 0) * 1536 + 512];
                unsigned uo0 = wp[(c + 0) * 1536 + 1024];
                unsigned ui1 = wp[(c + 1) * 1536];
                unsigned ug1 = wp[(c + 1) * 1536 + 512];
                unsigned uo1 = wp[(c + 1) * 1536 + 1024];
                gi += blo(ui0) * aA.x + bhi(ui0) * aA.y + blo(ui1) * aA.z + bhi(ui1) * aA.w;
                gg += blo(ug0) * aA.x + bhi(ug0) * aA.y + blo(ug1) * aA.z + bhi(ug1) * aA.w;
                go += blo(uo0) * aA.x + bhi(uo0) * aA.y + blo(uo1) * aA.z + bhi(uo1) * aA.w;
            }
        }
        const size_t m = (size_t)k * 128 + b;
        gi += pre_m_h[(m * 3 + 0) * 512 + tid];
        gg += pre_m_h[(m * 3 + 1) * 512 + tid];
        go += pre_m_h[(m * 3 + 2) * 512 + tid];
        float cc   = fast_sigmoid(gi) * fast_tanh(gg);
        float hnew = fast_sigmoid(go) * fast_tanh(cc);
        __syncthreads();
        hm[tid] = hnew;
        __syncthreads();
    }

    // ---- FC epilogue: out[b,c] = hm . fc_w[c] + fc_b[c], waves 0..2 ----
    if (wv < 3) {
        float p = 0.0f;
#pragma unroll
        for (int u = 0; u < 8; ++u) {
            int h = lane + 64 * u;
            p += hm[h] * fc_w[wv * 512 + h];
        }
#pragma unroll
        for (int off = 32; off; off >>= 1) p += __shfl_xor(p, off);
        if (lane == 0) out[b * 3 + wv] = p + fc_b[wv];
    }
}

extern "C" void kernel_launch(void* const* d_in, const int* in_sizes, int n_in,
                              void* d_out, int out_size, void* d_ws, size_t ws_size,
                              hipStream_t stream)
{
    (void)in_sizes; (void)n_in; (void)out_size;
    const int*   premise    = (const int*)d_in[0];
    const int*   hypothesis = (const int*)d_in[2];
    const float* embed  = (const float*)d_in[4];
    const float* w_e    = (const float*)d_in[5];
    const float* Ws     = (const float*)d_in[6];
    const float* Wt     = (const float*)d_in[7];
    const float* Wm     = (const float*)d_in[8];
    const float* Wih_p  = (const float*)d_in[9];
    const float* bih_p  = (const float*)d_in[10];
    const float* bhh_p  = (const float*)d_in[11];
    const float* Wih_h  = (const float*)d_in[12];
    const float* bih_h  = (const float*)d_in[13];
    const float* bhh_h  = (const float*)d_in[14];
    const float* Wih_m  = (const float*)d_in[15];
    const float* bih_m  = (const float*)d_in[16];
    const float* bhh_m  = (const float*)d_in[17];
    const float* fc_w   = (const float*)d_in[18];
    const float* fc_b   = (const float*)d_in[19];

    float* ws      = (float*)d_ws;
    float* h_s     = ws;                      // 8192*512
    float* h_t     = h_s    + 4194304;        // 8192*512 (reused below)
    float* pre_s   = h_t    + 4194304;
    float* pre_t   = pre_s  + 4194304;
    float* pre_m_h = pre_t  + 4194304;        // 8192*3*512
    // bf16-packed transposed weights alias h_t's buffer: transposes are
    // launched AFTER the last gemm that reads h_t (stream-ordered).
    unsigned* WmT2 = (unsigned*)h_t;          // 256*512 uints  (0.5 MB)
    unsigned* W3t2 = WmT2 + 131072;           // 256*1536 uints (1.5 MB)
    float* outp    = (float*)d_out;
    if (ws_size < (size_t)29556736 * 4) return;

    dim3 blk(256);

    // Phase A (parallel)
    gemm3_kernel<64, 3, 0, 1><<<dim3(128, 16), blk, 0, stream>>>(
        embed, premise, 300, Wih_p, 300, 300, bih_p, bhh_p, nullptr, h_s);
    gemm3_kernel<64, 3, 0, 1><<<dim3(128, 16), blk, 0, stream>>>(
        embed, hypothesis, 300, Wih_h, 300, 300, bih_h, bhh_h, nullptr, h_t);
    gemm3_kernel<64, 1, 3, 0><<<dim3(128, 16), blk, 0, stream>>>(
        h_s, nullptr, 512, Ws, 512, 512, nullptr, nullptr, nullptr, pre_s);
    gemm3_kernel<64, 1, 3, 0><<<dim3(128, 16), blk, 0, stream>>>(
        h_t, nullptr, 512, Wt, 512, 512, nullptr, nullptr, nullptr, pre_t);
    gemm3_kernel<64, 3, 1, 0><<<dim3(128, 16), blk, 0, stream>>>(
        h_t, nullptr, 512, Wih_m + 512, 1024, 512, bih_m, bhh_m, nullptr, pre_m_h);

    // Weight transposes (after h_t's last reader; outputs alias h_t space)
    trans_pack_kernel<<<dim3(8, 4, 1), blk, 0, stream>>>(Wm, 512, 0, WmT2, 512);
    trans_pack_kernel<<<dim3(8, 4, 3), blk, 0, stream>>>(Wih_m, 1024, 1, W3t2, 1536);

    // Phase B: 128 independent blocks (one per batch element), no grid sync
    phaseB_kernel<<<dim3(128), dim3(512), 0, stream>>>(
        pre_s, pre_t, h_s, pre_m_h, WmT2, W3t2, w_e, fc_w, fc_b, outp);
}